// Round 2
// baseline (134.115 us; speedup 1.0000x reference)
//
#include <hip/hip_runtime.h>
#include <hip/hip_bf16.h>
#include <hip/hip_fp16.h>

typedef _Float16 f16;
typedef __attribute__((ext_vector_type(4))) _Float16 f16x4;
typedef __attribute__((ext_vector_type(8))) _Float16 f16x8;
typedef __attribute__((ext_vector_type(4))) float f32x4;

#define DIM     2048
#define BROWS   8192
#define NCOLS   1221      // 111 nodes * 11
#define NPAD    1280      // padded to 10 tiles of 128
#define NNODES  111
#define BM      128
#define BN      128
#define BK      32
#define NKT     (DIM / BK)   // 64

// ---------------------------------------------------------------------------
// prep_b: write B in MFMA-fragment order, fp16.
// Chunk index = (((nt*64 + kt)*8 + g)*64 + l), each chunk 8 f16 (16 B):
//   chunk(nt,kt,g,l) = W-col (nt*128+g*16+(l&15)) , k-range kt*32+(l>>4)*8 .. +8
// where col c -> node n=c/11, slot k=c%11 ; cols >= 1221 are zero padding.
// ---------------------------------------------------------------------------
__global__ void prep_b(const float* __restrict__ W, f16* __restrict__ Bf) {
    int idx = blockIdx.x * 256 + threadIdx.x;        // 0 .. 327679 (1280 blocks)
    int l  = idx & 63;
    int g  = (idx >> 6) & 7;
    int kt = (idx >> 9) & 63;
    int nt = idx >> 15;
    int r = l & 15, q = l >> 4;
    int col = nt * 128 + g * 16 + r;
    int d0  = kt * 32 + q * 8;
    f16x8 v;
    if (col < NCOLS) {
        int n = col / 11, k = col - n * 11;
        const float* src = W + ((size_t)n * DIM + d0) * 11 + k;
        #pragma unroll
        for (int e = 0; e < 8; ++e) v[e] = (f16)src[(size_t)e * 11];
    } else {
        #pragma unroll
        for (int e = 0; e < 8; ++e) v[e] = (f16)0.f;
    }
    *(f16x8*)(Bf + (size_t)idx * 8) = v;
}

// ---------------------------------------------------------------------------
// GEMM: L[b][c] = sum_d x[b,d]*B[c,d].  128x128 tile, BK=32, 4 waves,
// fragment-linear LDS (conflict-free), 2-phase pipelined (stage t+1 while
// computing t; single __syncthreads per K-step, drain AFTER compute).
// ---------------------------------------------------------------------------
__global__ __launch_bounds__(256, 2) void gemm_f16(const float* __restrict__ X,
                                                   const f16* __restrict__ Bf,
                                                   float* __restrict__ L) {
    __shared__ __align__(16) f16 As[2][4096];   // 8 KB per buffer, chunk-linear
    __shared__ __align__(16) f16 Bs[2][4096];

    int bid = blockIdx.x;                        // 640 = 8 XCDs * 80
    int swz = (bid & 7) * 80 + (bid >> 3);
    int mt = swz / 10, nt = swz - mt * 10;

    int t = threadIdx.x;
    int w = t >> 6, l = t & 63;
    int r = l & 15, q = l >> 4;
    int wm = w >> 1, wn = w & 1;

    // A sources: this thread stages chunks (g=w) and (g=w+4):
    //   row mt*128 + g*16 + r, cols kt*32 + q*8 .. +8 (f32)
    const float* a_src0 = X + (size_t)(mt * 128 + w * 16 + r) * DIM + q * 8;
    const float* a_src1 = a_src0 + (size_t)64 * DIM;
    // B source: fragment-ordered, per kt one 8 KB image (4096 f16)
    const f16* b_base = Bf + (size_t)(nt * 64) * 4096;

    f32x4 acc[4][4];
    #pragma unroll
    for (int i = 0; i < 4; ++i)
        #pragma unroll
        for (int j = 0; j < 4; ++j) acc[i][j] = (f32x4)0.f;

    // ---- stage helpers (macro so dst buffer index stays simple) ----
#define STAGE_B(KT, CB)                                                          \
    {                                                                            \
        const f16* bs = b_base + (size_t)(KT) * 4096;                            \
        _Pragma("unroll")                                                        \
        for (int p = 0; p < 2; ++p) {                                            \
            __builtin_amdgcn_global_load_lds(                                    \
                (const __attribute__((address_space(1))) void*)(bs + (p*4 + w) * 512 + l * 8), \
                (__attribute__((address_space(3))) void*)(&Bs[CB][(p*4 + w) * 512]),           \
                16, 0, 0);                                                       \
        }                                                                        \
    }

    // prologue: stage kt=0 into buffer 0
    STAGE_B(0, 0)
    {
        f32x4 va0 = *(const f32x4*)(a_src0);
        f32x4 va1 = *(const f32x4*)(a_src0 + 4);
        f32x4 va2 = *(const f32x4*)(a_src1);
        f32x4 va3 = *(const f32x4*)(a_src1 + 4);
        f16x8 h0, h1;
        #pragma unroll
        for (int e = 0; e < 4; ++e) { h0[e] = (f16)va0[e]; h0[e+4] = (f16)va1[e];
                                      h1[e] = (f16)va2[e]; h1[e+4] = (f16)va3[e]; }
        *(f16x8*)(&As[0][(w * 64 + l) * 8])       = h0;
        *(f16x8*)(&As[0][((w + 4) * 64 + l) * 8]) = h1;
    }
    __syncthreads();

    int c = 0;
    for (int kt = 0; kt < NKT - 1; ++kt) {
        // (1) issue A loads for kt+1 (regs)
        const float* s0 = a_src0 + (size_t)(kt + 1) * BK;
        const float* s1 = a_src1 + (size_t)(kt + 1) * BK;
        f32x4 va0 = *(const f32x4*)(s0);
        f32x4 va1 = *(const f32x4*)(s0 + 4);
        f32x4 va2 = *(const f32x4*)(s1);
        f32x4 va3 = *(const f32x4*)(s1 + 4);
        // (2) issue B global->LDS for kt+1 into the other buffer
        STAGE_B(kt + 1, c ^ 1)
        // (3) fragments from current buffer (conflict-free: lane*16B linear)
        f16x8 af[4], bf[4];
        #pragma unroll
        for (int m = 0; m < 4; ++m) af[m] = *(const f16x8*)(&As[c][((wm*4 + m) * 64 + l) * 8]);
        #pragma unroll
        for (int n = 0; n < 4; ++n) bf[n] = *(const f16x8*)(&Bs[c][((wn*4 + n) * 64 + l) * 8]);
        // (4) MFMA
        #pragma unroll
        for (int m = 0; m < 4; ++m)
            #pragma unroll
            for (int n = 0; n < 4; ++n)
                acc[m][n] = __builtin_amdgcn_mfma_f32_16x16x32_f16(af[m], bf[n], acc[m][n], 0, 0, 0);
        // (5) cvt + write A(kt+1) into the other buffer
        f16x8 h0, h1;
        #pragma unroll
        for (int e = 0; e < 4; ++e) { h0[e] = (f16)va0[e]; h0[e+4] = (f16)va1[e];
                                      h1[e] = (f16)va2[e]; h1[e+4] = (f16)va3[e]; }
        *(f16x8*)(&As[c ^ 1][(w * 64 + l) * 8])       = h0;
        *(f16x8*)(&As[c ^ 1][((w + 4) * 64 + l) * 8]) = h1;
        // (6) one drain+barrier per K-step, AFTER compute
        __syncthreads();
        c ^= 1;
    }
    // tail: compute last tile
    {
        f16x8 af[4], bf[4];
        #pragma unroll
        for (int m = 0; m < 4; ++m) af[m] = *(const f16x8*)(&As[c][((wm*4 + m) * 64 + l) * 8]);
        #pragma unroll
        for (int n = 0; n < 4; ++n) bf[n] = *(const f16x8*)(&Bs[c][((wn*4 + n) * 64 + l) * 8]);
        #pragma unroll
        for (int m = 0; m < 4; ++m)
            #pragma unroll
            for (int n = 0; n < 4; ++n)
                acc[m][n] = __builtin_amdgcn_mfma_f32_16x16x32_f16(af[m], bf[n], acc[m][n], 0, 0, 0);
    }
#undef STAGE_B

    // C write: col = lane&15, row = (lane>>4)*4 + j  (verified round 1)
    #pragma unroll
    for (int m = 0; m < 4; ++m) {
        int row = mt * 128 + wm * 64 + m * 16 + q * 4;
        #pragma unroll
        for (int n = 0; n < 4; ++n) {
            int col = nt * 128 + wn * 64 + n * 16 + r;
            #pragma unroll
            for (int j = 0; j < 4; ++j)
                L[(size_t)(row + j) * NPAD + col] = acc[m][n][j];
        }
    }
}

// ---------- epilogue: softmax per node (k=11) + 3-level product tree ----------
__global__ void tree_epi(const float* __restrict__ L, const float* __restrict__ bias,
                         float* __restrict__ out) {
    __shared__ float P[4][NNODES * 11];
    int w = threadIdx.x >> 6, l = threadIdx.x & 63;
    int row = blockIdx.x * 4 + w;
    const float* Lr = L + (size_t)row * NPAD;

    for (int n = l; n < NNODES; n += 64) {
        float v[11], mx = -1e30f;
        #pragma unroll
        for (int k = 0; k < 11; ++k) { v[k] = Lr[n * 11 + k] + bias[n * 11 + k]; mx = fmaxf(mx, v[k]); }
        float s = 0.f;
        #pragma unroll
        for (int k = 0; k < 11; ++k) { v[k] = __expf(v[k] - mx); s += v[k]; }
        float inv = 1.f / s;
        #pragma unroll
        for (int k = 0; k < 11; ++k) P[w][n * 11 + k] = v[k] * inv;
    }
    __syncthreads();
    const float* Pw = P[w];
    for (int c = l; c < 1000; c += 64) {
        int i  = c / 100;
        int j  = (c % 100) / 10;
        int mm = c % 10;
        float p = Pw[1 + i] * Pw[(1 + i) * 11 + 1 + j] * Pw[(11 + 10 * i + j) * 11 + 1 + mm];
        out[(size_t)row * 1000 + c] = p;
    }
    if (row == 0 && threadIdx.x == 0) out[(size_t)BROWS * 1000] = 0.f;  // penalty
}

extern "C" void kernel_launch(void* const* d_in, const int* in_sizes, int n_in,
                              void* d_out, int out_size, void* d_ws, size_t ws_size,
                              hipStream_t stream) {
    const float* x    = (const float*)d_in[0];
    // d_in[1] = labels (unused by reference computation)
    const float* W    = (const float*)d_in[2];
    const float* bias = (const float*)d_in[3];
    float* out = (float*)d_out;

    // ws layout: Bf fp16 fragment-ordered [1280*2048] = 5,242,880 B ;
    //            L f32 [8192][1280] = 41,943,040 B
    f16*   Bf = (f16*)d_ws;
    float* L  = (float*)((char*)d_ws + (size_t)NPAD * DIM * sizeof(f16));

    prep_b  <<<NPAD, 256, 0, stream>>>(W, Bf);
    gemm_f16<<<(BROWS / BM) * (NPAD / BN), 256, 0, stream>>>(x, Bf, L);
    tree_epi<<<BROWS / 4, 256, 0, stream>>>(L, bias, out);
}

// Round 3
// 90.095 us; speedup vs baseline: 1.4886x; 1.4886x over previous
//
#include <hip/hip_runtime.h>
#include <hip/hip_bf16.h>
#include <hip/hip_fp16.h>

typedef _Float16 f16;
typedef __attribute__((ext_vector_type(8))) _Float16 f16x8;
typedef __attribute__((ext_vector_type(4))) float f32x4;

#define DIM     2048
#define BROWS   8192
#define NCOLS   1221      // 111 nodes * 11
#define NPAD    1280      // 10 tiles of 128
#define NNODES  111
#define BM      128
#define BN      128
#define BK      64
#define NKT     (DIM / BK)    // 32
#define MT      (BROWS / BM)  // 64
#define NT      (NPAD / BN)   // 10
// Fragment image per (tile, kt): 1024 chunks x 16B = 16 KB = 8192 f16.
// chunk c = (kk*8 + g)*64 + l ; lane l (r=l&15,q=l>>4) holds
//   row = g*16 + r , k = kk*32 + q*8 .. +8   (within the 128x64 tile)

// ---------------------------------------------------------------------------
// prep_x: x f32 [8192][2048]  ->  Xf f16 fragment-ordered (64 mt x 32 kt images)
// Permutation through padded LDS: coalesced read AND coalesced write.
// ---------------------------------------------------------------------------
__global__ __launch_bounds__(256) void prep_x(const float* __restrict__ X,
                                              f16* __restrict__ Xf) {
    __shared__ float T[128 * 68];              // [128][68] pad -> conflict-min
    int blk = blockIdx.x;                      // mt*32 + kt
    int mt = blk >> 5, kt = blk & 31;
    int t = threadIdx.x;
    int row = t >> 1, half = t & 1;
    const float* src = X + (size_t)(mt * 128 + row) * DIM + kt * 64 + half * 32;
    float* dst = T + row * 68 + half * 32;
    #pragma unroll
    for (int i = 0; i < 8; ++i) ((f32x4*)dst)[i] = ((const f32x4*)src)[i];
    __syncthreads();
    int w = t >> 6, l = t & 63, r = l & 15, q = l >> 4;
    f16* out = Xf + (size_t)blk * 8192;
    #pragma unroll
    for (int p = 0; p < 4; ++p) {
        int gk = p * 4 + w;                    // = kk*8 + g
        int kk = gk >> 3, g = gk & 7;
        const float* s = T + (g * 16 + r) * 68 + kk * 32 + q * 8;
        f32x4 a = *(const f32x4*)s;
        f32x4 b = *(const f32x4*)(s + 4);
        f16x8 h;
        h[0] = (f16)a[0]; h[1] = (f16)a[1]; h[2] = (f16)a[2]; h[3] = (f16)a[3];
        h[4] = (f16)b[0]; h[5] = (f16)b[1]; h[6] = (f16)b[2]; h[7] = (f16)b[3];
        *(f16x8*)(out + (size_t)(p * 256 + t) * 8) = h;   // coalesced
    }
}

// ---------------------------------------------------------------------------
// prep_b: W f32 [111][2048][11] -> Bf f16 fragment-ordered (10 nt x 32 kt)
// col c -> node c/11, slot c%11 ; cols >= 1221 zero.
// ---------------------------------------------------------------------------
__global__ void prep_b(const float* __restrict__ W, f16* __restrict__ Bf) {
    int idx = blockIdx.x * 256 + threadIdx.x;  // 327,680 = 320 images x 1024
    int c = idx & 1023, img = idx >> 10;       // img = nt*32 + kt
    int nt = img >> 5, kt = img & 31;
    int kk = c >> 9, g = (c >> 6) & 7, l = c & 63, r = l & 15, q = l >> 4;
    int col = nt * 128 + g * 16 + r;
    int d0  = kt * 64 + kk * 32 + q * 8;
    f16x8 v;
    if (col < NCOLS) {
        int n = col / 11, k = col - n * 11;
        const float* src = W + ((size_t)n * DIM + d0) * 11 + k;
        #pragma unroll
        for (int e = 0; e < 8; ++e) v[e] = (f16)src[(size_t)e * 11];
    } else {
        #pragma unroll
        for (int e = 0; e < 8; ++e) v[e] = (f16)0.f;
    }
    *(f16x8*)(Bf + (size_t)idx * 8) = v;
}

// ---------------------------------------------------------------------------
// GEMM (m97 clone): 128x128 tile, BK=64, 4 waves, single-buffer 2-barrier loop,
// ALL staging via global_load_lds (16B), fragment-linear LDS, 32 MFMA/K-step.
// ---------------------------------------------------------------------------
__global__ __launch_bounds__(256) void gemm_f16(const f16* __restrict__ Xf,
                                                const f16* __restrict__ Bf,
                                                f16* __restrict__ Lh) {
    __shared__ __align__(16) f16 As[8192];     // 16 KB
    __shared__ __align__(16) f16 Bs[8192];     // 16 KB

    int bid = blockIdx.x;                      // 640 = 8 XCDs * 80
    int swz = (bid & 7) * 80 + (bid >> 3);
    int mt = swz / 10, nt = swz - mt * 10;

    int t = threadIdx.x, w = t >> 6, l = t & 63, r = l & 15, q = l >> 4;
    int wm = w >> 1, wn = w & 1;

    const f16* abase = Xf + (size_t)(mt * 32) * 8192 + (size_t)t * 8;
    const f16* bbase = Bf + (size_t)(nt * 32) * 8192 + (size_t)t * 8;

    f32x4 acc[4][4];
    #pragma unroll
    for (int i = 0; i < 4; ++i)
        #pragma unroll
        for (int j = 0; j < 4; ++j) acc[i][j] = (f32x4)0.f;

    for (int kt = 0; kt < NKT; ++kt) {
        __syncthreads();                       // protect buffer reuse
        const f16* asrc = abase + (size_t)kt * 8192;
        const f16* bsrc = bbase + (size_t)kt * 8192;
        #pragma unroll
        for (int p = 0; p < 4; ++p) {
            __builtin_amdgcn_global_load_lds(
                (const __attribute__((address_space(1))) void*)(asrc + p * 2048),
                (__attribute__((address_space(3))) void*)(As + p * 2048 + w * 512),
                16, 0, 0);
            __builtin_amdgcn_global_load_lds(
                (const __attribute__((address_space(1))) void*)(bsrc + p * 2048),
                (__attribute__((address_space(3))) void*)(Bs + p * 2048 + w * 512),
                16, 0, 0);
        }
        __syncthreads();                       // drains vmcnt (compiler-inserted)
        #pragma unroll
        for (int kk = 0; kk < 2; ++kk) {
            f16x8 af[4], bf[4];
            #pragma unroll
            for (int m = 0; m < 4; ++m)
                af[m] = *(const f16x8*)(As + ((size_t)((kk * 8 + wm * 4 + m) * 64 + l)) * 8);
            #pragma unroll
            for (int n = 0; n < 4; ++n)
                bf[n] = *(const f16x8*)(Bs + ((size_t)((kk * 8 + wn * 4 + n) * 64 + l)) * 8);
            #pragma unroll
            for (int m = 0; m < 4; ++m)
                #pragma unroll
                for (int n = 0; n < 4; ++n)
                    acc[m][n] = __builtin_amdgcn_mfma_f32_16x16x32_f16(af[m], bf[n], acc[m][n], 0, 0, 0);
        }
    }

    // C write (f16): col = lane&15, row = (lane>>4)*4 + j (verified r1/r2)
    #pragma unroll
    for (int m = 0; m < 4; ++m) {
        int row = mt * 128 + wm * 64 + m * 16 + q * 4;
        #pragma unroll
        for (int n = 0; n < 4; ++n) {
            int col = nt * 128 + wn * 64 + n * 16 + r;
            #pragma unroll
            for (int j = 0; j < 4; ++j)
                Lh[(size_t)(row + j) * NPAD + col] = (f16)acc[m][n][j];
        }
    }
}

// ---------- epilogue: softmax per node (k=11) + 3-level product tree ----------
__global__ void tree_epi(const f16* __restrict__ L, const float* __restrict__ bias,
                         float* __restrict__ out) {
    __shared__ float P[4][NNODES * 11];
    int w = threadIdx.x >> 6, l = threadIdx.x & 63;
    int row = blockIdx.x * 4 + w;
    const f16* Lr = L + (size_t)row * NPAD;

    for (int n = l; n < NNODES; n += 64) {
        float v[11], mx = -1e30f;
        #pragma unroll
        for (int k = 0; k < 11; ++k) { v[k] = (float)Lr[n * 11 + k] + bias[n * 11 + k]; mx = fmaxf(mx, v[k]); }
        float s = 0.f;
        #pragma unroll
        for (int k = 0; k < 11; ++k) { v[k] = __expf(v[k] - mx); s += v[k]; }
        float inv = 1.f / s;
        #pragma unroll
        for (int k = 0; k < 11; ++k) P[w][n * 11 + k] = v[k] * inv;
    }
    __syncthreads();
    const float* Pw = P[w];
    for (int c = l; c < 1000; c += 64) {
        int i  = c / 100;
        int j  = (c % 100) / 10;
        int mm = c % 10;
        float p = Pw[1 + i] * Pw[(1 + i) * 11 + 1 + j] * Pw[(11 + 10 * i + j) * 11 + 1 + mm];
        out[(size_t)row * 1000 + c] = p;
    }
    if (row == 0 && threadIdx.x == 0) out[(size_t)BROWS * 1000] = 0.f;  // penalty
}

extern "C" void kernel_launch(void* const* d_in, const int* in_sizes, int n_in,
                              void* d_out, int out_size, void* d_ws, size_t ws_size,
                              hipStream_t stream) {
    const float* x    = (const float*)d_in[0];
    // d_in[1] = labels (unused)
    const float* W    = (const float*)d_in[2];
    const float* bias = (const float*)d_in[3];
    float* out = (float*)d_out;

    // ws layout:
    //   Xf  f16 fragment-ordered  33,554,432 B
    //   Bf  f16 fragment-ordered   5,242,880 B
    //   Lh  f16 [8192][1280]      20,971,520 B   (total 59,768,832 B)
    f16* Xf = (f16*)d_ws;
    f16* Bf = (f16*)((char*)d_ws + 33554432);
    f16* Lh = (f16*)((char*)d_ws + 38797312);

    prep_x <<<MT * NKT, 256, 0, stream>>>(x, Xf);
    prep_b <<<1280, 256, 0, stream>>>(W, Bf);
    gemm_f16<<<MT * NT, 256, 0, stream>>>(Xf, Bf, Lh);
    tree_epi<<<BROWS / 4, 256, 0, stream>>>(Lh, bias, out);
}

// Round 4
// 87.625 us; speedup vs baseline: 1.5306x; 1.0282x over previous
//
#include <hip/hip_runtime.h>
#include <hip/hip_bf16.h>
#include <hip/hip_fp16.h>

typedef _Float16 f16;
typedef __attribute__((ext_vector_type(8))) _Float16 f16x8;
typedef __attribute__((ext_vector_type(4))) float f32x4;

#define DIM     2048
#define BROWS   8192
#define NCOLS   1221      // 111 nodes * 11
#define NPAD    1280      // 10 tiles of 128
#define NNODES  111
#define BM      128
#define BN      128
#define BK      64
#define NKT     (DIM / BK)    // 32
#define MT      (BROWS / BM)  // 64
#define NT      (NPAD / BN)   // 10
// Fragment image per (tile, kt): 1024 chunks x 16B = 16 KB = 8192 f16.
// chunk c = (kk*8 + g)*64 + l ; lane l (r=l&15,q=l>>4) holds
//   row = g*16 + r , k = kk*32 + q*8 .. +8   (within the 128x64 tile)

// ---------------------------------------------------------------------------
// prep_x: x f32 [8192][2048]  ->  Xf f16 fragment-ordered (64 mt x 32 kt images)
// Permutation through padded LDS: coalesced read AND coalesced write.
// ---------------------------------------------------------------------------
__global__ __launch_bounds__(256) void prep_x(const float* __restrict__ X,
                                              f16* __restrict__ Xf) {
    __shared__ float T[128 * 68];              // [128][68] pad -> conflict-min
    int blk = blockIdx.x;                      // mt*32 + kt
    int mt = blk >> 5, kt = blk & 31;
    int t = threadIdx.x;
    int row = t >> 1, half = t & 1;
    const float* src = X + (size_t)(mt * 128 + row) * DIM + kt * 64 + half * 32;
    float* dst = T + row * 68 + half * 32;
    #pragma unroll
    for (int i = 0; i < 8; ++i) ((f32x4*)dst)[i] = ((const f32x4*)src)[i];
    __syncthreads();
    int w = t >> 6, l = t & 63, r = l & 15, q = l >> 4;
    f16* out = Xf + (size_t)blk * 8192;
    #pragma unroll
    for (int p = 0; p < 4; ++p) {
        int gk = p * 4 + w;                    // = kk*8 + g
        int kk = gk >> 3, g = gk & 7;
        const float* s = T + (g * 16 + r) * 68 + kk * 32 + q * 8;
        f32x4 a = *(const f32x4*)s;
        f32x4 b = *(const f32x4*)(s + 4);
        f16x8 h;
        h[0] = (f16)a[0]; h[1] = (f16)a[1]; h[2] = (f16)a[2]; h[3] = (f16)a[3];
        h[4] = (f16)b[0]; h[5] = (f16)b[1]; h[6] = (f16)b[2]; h[7] = (f16)b[3];
        *(f16x8*)(out + (size_t)(p * 256 + t) * 8) = h;   // coalesced
    }
}

// ---------------------------------------------------------------------------
// prep_b: W f32 [111][2048][11] -> Bf f16 fragment-ordered (10 nt x 32 kt)
// col c -> node c/11, slot c%11 ; cols >= 1221 zero.
// ---------------------------------------------------------------------------
__global__ void prep_b(const float* __restrict__ W, f16* __restrict__ Bf) {
    int idx = blockIdx.x * 256 + threadIdx.x;  // 327,680 = 320 images x 1024
    int c = idx & 1023, img = idx >> 10;       // img = nt*32 + kt
    int nt = img >> 5, kt = img & 31;
    int kk = c >> 9, g = (c >> 6) & 7, l = c & 63, r = l & 15, q = l >> 4;
    int col = nt * 128 + g * 16 + r;
    int d0  = kt * 64 + kk * 32 + q * 8;
    f16x8 v;
    if (col < NCOLS) {
        int n = col / 11, k = col - n * 11;
        const float* src = W + ((size_t)n * DIM + d0) * 11 + k;
        #pragma unroll
        for (int e = 0; e < 8; ++e) v[e] = (f16)src[(size_t)e * 11];
    } else {
        #pragma unroll
        for (int e = 0; e < 8; ++e) v[e] = (f16)0.f;
    }
    *(f16x8*)(Bf + (size_t)idx * 8) = v;
}

// ---------------------------------------------------------------------------
// GEMM: 128x128 tile, BK=64, 8 waves (wave-tile 64x32), single-buffer
// 2-barrier loop, ALL staging via global_load_lds (16B), fragment-linear LDS.
// ---------------------------------------------------------------------------
__global__ __launch_bounds__(512, 4) void gemm_f16(const f16* __restrict__ Xf,
                                                   const f16* __restrict__ Bf,
                                                   f16* __restrict__ Lh) {
    __shared__ __align__(16) f16 As[8192];     // 16 KB
    __shared__ __align__(16) f16 Bs[8192];     // 16 KB

    int bid = blockIdx.x;                      // 640 = 8 XCDs * 80
    int swz = (bid & 7) * 80 + (bid >> 3);
    int mt = swz / 10, nt = swz - mt * 10;

    int t = threadIdx.x, w = t >> 6, l = t & 63, r = l & 15, q = l >> 4;
    int wm = w >> 2, wn = w & 3;               // 2 x 4 wave grid, wave tile 64x32

    const f16* abase = Xf + (size_t)(mt * 32) * 8192 + (size_t)t * 8;
    const f16* bbase = Bf + (size_t)(nt * 32) * 8192 + (size_t)t * 8;

    f32x4 acc[4][2];
    #pragma unroll
    for (int i = 0; i < 4; ++i)
        #pragma unroll
        for (int j = 0; j < 2; ++j) acc[i][j] = (f32x4)0.f;

    for (int kt = 0; kt < NKT; ++kt) {
        __syncthreads();                       // protect buffer reuse
        const f16* asrc = abase + (size_t)kt * 8192;
        const f16* bsrc = bbase + (size_t)kt * 8192;
        #pragma unroll
        for (int p = 0; p < 2; ++p) {          // 512 thr x 16B = 8KB per round
            __builtin_amdgcn_global_load_lds(
                (const __attribute__((address_space(1))) void*)(asrc + p * 4096),
                (__attribute__((address_space(3))) void*)(As + p * 4096 + w * 512),
                16, 0, 0);
            __builtin_amdgcn_global_load_lds(
                (const __attribute__((address_space(1))) void*)(bsrc + p * 4096),
                (__attribute__((address_space(3))) void*)(Bs + p * 4096 + w * 512),
                16, 0, 0);
        }
        __syncthreads();                       // drains vmcnt (compiler-inserted)
        #pragma unroll
        for (int kk = 0; kk < 2; ++kk) {
            f16x8 af[4], bf[2];
            #pragma unroll
            for (int m = 0; m < 4; ++m)
                af[m] = *(const f16x8*)(As + ((size_t)((kk * 8 + wm * 4 + m) * 64 + l)) * 8);
            #pragma unroll
            for (int n = 0; n < 2; ++n)
                bf[n] = *(const f16x8*)(Bs + ((size_t)((kk * 8 + wn * 2 + n) * 64 + l)) * 8);
            #pragma unroll
            for (int m = 0; m < 4; ++m)
                #pragma unroll
                for (int n = 0; n < 2; ++n)
                    acc[m][n] = __builtin_amdgcn_mfma_f32_16x16x32_f16(af[m], bf[n], acc[m][n], 0, 0, 0);
        }
    }

    // C write (f16): col = lane&15, row = (lane>>4)*4 + j (verified r1-r3)
    #pragma unroll
    for (int m = 0; m < 4; ++m) {
        int row = mt * 128 + wm * 64 + m * 16 + q * 4;
        #pragma unroll
        for (int n = 0; n < 2; ++n) {
            int col = nt * 128 + wn * 32 + n * 16 + r;
            #pragma unroll
            for (int j = 0; j < 4; ++j)
                Lh[(size_t)(row + j) * NPAD + col] = (f16)acc[m][n][j];
        }
    }
}

// ---------- epilogue: softmax per node (k=11) + 3-level product tree ----------
__global__ void tree_epi(const f16* __restrict__ L, const float* __restrict__ bias,
                         float* __restrict__ out) {
    __shared__ float P[4][NNODES * 11];
    int w = threadIdx.x >> 6, l = threadIdx.x & 63;
    int row = blockIdx.x * 4 + w;
    const f16* Lr = L + (size_t)row * NPAD;

    for (int n = l; n < NNODES; n += 64) {
        float v[11], mx = -1e30f;
        #pragma unroll
        for (int k = 0; k < 11; ++k) { v[k] = (float)Lr[n * 11 + k] + bias[n * 11 + k]; mx = fmaxf(mx, v[k]); }
        float s = 0.f;
        #pragma unroll
        for (int k = 0; k < 11; ++k) { v[k] = __expf(v[k] - mx); s += v[k]; }
        float inv = 1.f / s;
        #pragma unroll
        for (int k = 0; k < 11; ++k) P[w][n * 11 + k] = v[k] * inv;
    }
    __syncthreads();
    const float* Pw = P[w];
    for (int c = l; c < 1000; c += 64) {
        int i  = c / 100;
        int j  = (c % 100) / 10;
        int mm = c % 10;
        float p = Pw[1 + i] * Pw[(1 + i) * 11 + 1 + j] * Pw[(11 + 10 * i + j) * 11 + 1 + mm];
        out[(size_t)row * 1000 + c] = p;
    }
    if (row == 0 && threadIdx.x == 0) out[(size_t)BROWS * 1000] = 0.f;  // penalty
}

extern "C" void kernel_launch(void* const* d_in, const int* in_sizes, int n_in,
                              void* d_out, int out_size, void* d_ws, size_t ws_size,
                              hipStream_t stream) {
    const float* x    = (const float*)d_in[0];
    // d_in[1] = labels (unused)
    const float* W    = (const float*)d_in[2];
    const float* bias = (const float*)d_in[3];
    float* out = (float*)d_out;

    // ws layout:
    //   Xf  f16 fragment-ordered  33,554,432 B
    //   Bf  f16 fragment-ordered   5,242,880 B
    //   Lh  f16 [8192][1280]      20,971,520 B   (total 59,768,832 B)
    f16* Xf = (f16*)d_ws;
    f16* Bf = (f16*)((char*)d_ws + 33554432);
    f16* Lh = (f16*)((char*)d_ws + 38797312);

    prep_x <<<MT * NKT, 256, 0, stream>>>(x, Xf);
    prep_b <<<1280, 256, 0, stream>>>(W, Bf);
    gemm_f16<<<MT * NT, 512, 0, stream>>>(Xf, Bf, Lh);
    tree_epi<<<BROWS / 4, 256, 0, stream>>>(Lh, bias, out);
}